// Round 2
// baseline (635.312 us; speedup 1.0000x reference)
//
#include <hip/hip_runtime.h>

typedef unsigned short u16;
typedef __bf16 bf16x8 __attribute__((ext_vector_type(8)));
typedef float f32x4 __attribute__((ext_vector_type(4)));

#define DIMD 512
#define SEQN 2048
#define NB   8
#define NH   8
#define DH   64
#define BHN  (NB*NH)          // 64
#define MROWS (NB*SEQN)       // 16384

__device__ __forceinline__ u16 f2bf(float f) {
  union { float f; unsigned u; } x; x.f = f;
  unsigned r = x.u + 0x7fffu + ((x.u >> 16) & 1u);
  return (u16)(r >> 16);
}
__device__ __forceinline__ float bf2f(u16 u) {
  union { unsigned u; float f; } x; x.u = ((unsigned)u) << 16;
  return x.f;
}

// ---------------- LayerNorm: one wave per row of 512. fp32 in -> bf16 out --
__global__ __launch_bounds__(256) void ln_kernel(
    const float* __restrict__ x, const float* __restrict__ gamma,
    const float* __restrict__ beta, u16* __restrict__ xn) {
  int row = blockIdx.x * 4 + (threadIdx.x >> 6);
  int lane = threadIdx.x & 63;
  const float* xr = x + (size_t)row * DIMD;
  float f[8], g[8], b[8];
  *(float4*)&f[0] = *(const float4*)(xr + lane * 8);
  *(float4*)&f[4] = *(const float4*)(xr + lane * 8 + 4);
  *(float4*)&g[0] = *(const float4*)(gamma + lane * 8);
  *(float4*)&g[4] = *(const float4*)(gamma + lane * 8 + 4);
  *(float4*)&b[0] = *(const float4*)(beta + lane * 8);
  *(float4*)&b[4] = *(const float4*)(beta + lane * 8 + 4);
  float sum = 0.f, sq = 0.f;
#pragma unroll
  for (int i = 0; i < 8; ++i) { sum += f[i]; sq += f[i] * f[i]; }
#pragma unroll
  for (int off = 1; off < 64; off <<= 1) {
    sum += __shfl_xor(sum, off, 64);
    sq  += __shfl_xor(sq, off, 64);
  }
  float mean = sum * (1.0f / DIMD);
  float var = sq * (1.0f / DIMD) - mean * mean;
  float rstd = rsqrtf(var + 1e-6f);
  union { uint4 v; u16 s[8]; } uo;
#pragma unroll
  for (int i = 0; i < 8; ++i)
    uo.s[i] = f2bf((f[i] - mean) * rstd * g[i] + b[i]);
  *(uint4*)(xn + (size_t)row * DIMD + lane * 8) = uo.v;
}

// ---------------- QKV GEMM: C[m,n] = xn[m,:] . w_qkv[n,:]  (B^T layout) ---
// A bf16, B fp32 (converted during staging). Epilogue scatters q/k/vt (bf16).
__global__ __launch_bounds__(256) void qkv_gemm(
    const u16* __restrict__ A, const float* __restrict__ Bm,
    u16* __restrict__ qo, u16* __restrict__ ko, u16* __restrict__ vto) {
  __shared__ __align__(16) u16 la[128 * 40];
  __shared__ __align__(16) u16 lb[128 * 40];
  const int K = DIMD;
  int tid = threadIdx.x;
  int bm = blockIdx.x, bn = blockIdx.y;
  int wid = tid >> 6, lane = tid & 63, lm = lane & 15, quad = lane >> 4;
  int wm = wid >> 1, wn = wid & 1;
  f32x4 acc[4][4] = {};
  const u16* Ab = A + (size_t)(bm * 128) * K;
  const float* Bb = Bm + (size_t)(bn * 128) * K;
  for (int k0 = 0; k0 < K; k0 += 32) {
    __syncthreads();
#pragma unroll
    for (int r = 0; r < 2; ++r) {
      int ch = tid + r * 256;
      int row = ch >> 2, cc = ch & 3;
      uint4 va = *(const uint4*)(Ab + (size_t)row * K + k0 + cc * 8);
      float4 f0 = *(const float4*)(Bb + (size_t)row * K + k0 + cc * 8);
      float4 f1 = *(const float4*)(Bb + (size_t)row * K + k0 + cc * 8 + 4);
      union { uint4 v; u16 s[8]; } wb;
      wb.s[0] = f2bf(f0.x); wb.s[1] = f2bf(f0.y);
      wb.s[2] = f2bf(f0.z); wb.s[3] = f2bf(f0.w);
      wb.s[4] = f2bf(f1.x); wb.s[5] = f2bf(f1.y);
      wb.s[6] = f2bf(f1.z); wb.s[7] = f2bf(f1.w);
      *(uint4*)&la[row * 40 + cc * 8] = va;
      *(uint4*)&lb[row * 40 + cc * 8] = wb.v;
    }
    __syncthreads();
    bf16x8 af[4], bfr[4];
#pragma unroll
    for (int i = 0; i < 4; ++i)
      af[i] = *(const bf16x8*)&la[(wm * 64 + i * 16 + lm) * 40 + quad * 8];
#pragma unroll
    for (int j = 0; j < 4; ++j)
      bfr[j] = *(const bf16x8*)&lb[(wn * 64 + j * 16 + lm) * 40 + quad * 8];
#pragma unroll
    for (int i = 0; i < 4; ++i)
#pragma unroll
      for (int j = 0; j < 4; ++j)
        acc[i][j] = __builtin_amdgcn_mfma_f32_16x16x32_bf16(af[i], bfr[j], acc[i][j], 0, 0, 0);
  }
#pragma unroll
  for (int i = 0; i < 4; ++i) {
#pragma unroll
    for (int j = 0; j < 4; ++j) {
      int col = bn * 128 + wn * 64 + j * 16 + lm;
      int part = col >> 9, rem = col & 511;
      int h = rem >> 6, d = rem & 63;
#pragma unroll
      for (int r = 0; r < 4; ++r) {
        int rg = bm * 128 + wm * 64 + i * 16 + quad * 4 + r;
        int b = rg >> 11, nn = rg & 2047;
        int bh = b * NH + h;
        u16 val = f2bf(acc[i][j][r]);
        if (part == 0)      qo[((size_t)bh * SEQN + nn) * DH + d] = val;
        else if (part == 1) ko[((size_t)bh * SEQN + nn) * DH + d] = val;
        else                vto[((size_t)bh * DH + d) * SEQN + nn] = val;
      }
    }
  }
}

// ---------------- Flash attention (all bf16 I/O, fp32 softmax) ----------------
// grid: (N/64, B*H). block 256 = 4 waves; wave w owns Q rows [q0+16w, q0+16w+16)
__global__ __launch_bounds__(256) void attn_kernel(
    const u16* __restrict__ q, const u16* __restrict__ k,
    const u16* __restrict__ vt, u16* __restrict__ att) {
  __shared__ __align__(16) u16 plds[4 * 16 * 72];
  int bh = blockIdx.y;
  int q0 = blockIdx.x * 64;
  int wid = threadIdx.x >> 6, lane = threadIdx.x & 63;
  int lm = lane & 15, quad = lane >> 4;
  int qrow = q0 + wid * 16;
  const u16* qb = q + (size_t)bh * SEQN * DH;
  const u16* kb = k + (size_t)bh * SEQN * DH;
  const u16* vb = vt + (size_t)bh * DH * SEQN;
  u16* pw = plds + wid * 16 * 72;

  bf16x8 qf[2];
#pragma unroll
  for (int c = 0; c < 2; ++c)
    qf[c] = *(const bf16x8*)(qb + (size_t)(qrow + lm) * DH + c * 32 + quad * 8);

  f32x4 O[4] = {};
  float mrow[4], lrow[4];
#pragma unroll
  for (int r = 0; r < 4; ++r) { mrow[r] = -__builtin_inff(); lrow[r] = 0.f; }

  for (int j0 = 0; j0 < SEQN; j0 += 64) {
    f32x4 s[4];
#pragma unroll
    for (int js = 0; js < 4; ++js) {
      bf16x8 kf0 = *(const bf16x8*)(kb + (size_t)(j0 + js * 16 + lm) * DH + quad * 8);
      bf16x8 kf1 = *(const bf16x8*)(kb + (size_t)(j0 + js * 16 + lm) * DH + 32 + quad * 8);
      f32x4 z = {0.f, 0.f, 0.f, 0.f};
      z = __builtin_amdgcn_mfma_f32_16x16x32_bf16(qf[0], kf0, z, 0, 0, 0);
      z = __builtin_amdgcn_mfma_f32_16x16x32_bf16(qf[1], kf1, z, 0, 0, 0);
      s[js] = z * 0.125f;   // 1/sqrt(64)
    }
    float mloc[4];
#pragma unroll
    for (int r = 0; r < 4; ++r)
      mloc[r] = fmaxf(fmaxf(s[0][r], s[1][r]), fmaxf(s[2][r], s[3][r]));
#pragma unroll
    for (int off = 1; off < 16; off <<= 1)
#pragma unroll
      for (int r = 0; r < 4; ++r)
        mloc[r] = fmaxf(mloc[r], __shfl_xor(mloc[r], off, 64));
    float alpha[4];
#pragma unroll
    for (int r = 0; r < 4; ++r) {
      float mn = fmaxf(mrow[r], mloc[r]);
      alpha[r] = __expf(mrow[r] - mn);
      mrow[r] = mn;
    }
    float rs[4] = {0.f, 0.f, 0.f, 0.f};
    u16 pb[4][4];
#pragma unroll
    for (int js = 0; js < 4; ++js)
#pragma unroll
      for (int r = 0; r < 4; ++r) {
        float p = __expf(s[js][r] - mrow[r]);
        rs[r] += p;
        pb[js][r] = f2bf(p);
      }
#pragma unroll
    for (int off = 1; off < 16; off <<= 1)
#pragma unroll
      for (int r = 0; r < 4; ++r)
        rs[r] += __shfl_xor(rs[r], off, 64);
#pragma unroll
    for (int r = 0; r < 4; ++r)
      lrow[r] = lrow[r] * alpha[r] + rs[r];
#pragma unroll
    for (int d = 0; d < 4; ++d)
#pragma unroll
      for (int r = 0; r < 4; ++r)
        O[d][r] *= alpha[r];
    // P (C-layout) -> LDS -> A-layout (per-wave region, no block sync needed)
#pragma unroll
    for (int js = 0; js < 4; ++js)
#pragma unroll
      for (int r = 0; r < 4; ++r)
        pw[(quad * 4 + r) * 72 + js * 16 + lm] = pb[js][r];
    bf16x8 pa0 = *(const bf16x8*)&pw[lm * 72 + quad * 8];
    bf16x8 pa1 = *(const bf16x8*)&pw[lm * 72 + 32 + quad * 8];
#pragma unroll
    for (int d = 0; d < 4; ++d) {
      bf16x8 v0 = *(const bf16x8*)(vb + (size_t)(d * 16 + lm) * SEQN + j0 + quad * 8);
      bf16x8 v1 = *(const bf16x8*)(vb + (size_t)(d * 16 + lm) * SEQN + j0 + 32 + quad * 8);
      O[d] = __builtin_amdgcn_mfma_f32_16x16x32_bf16(pa0, v0, O[d], 0, 0, 0);
      O[d] = __builtin_amdgcn_mfma_f32_16x16x32_bf16(pa1, v1, O[d], 0, 0, 0);
    }
  }
  int b = bh >> 3, h = bh & 7;
#pragma unroll
  for (int r = 0; r < 4; ++r) {
    float inv = 1.0f / lrow[r];
    int row = qrow + quad * 4 + r;
#pragma unroll
    for (int d = 0; d < 4; ++d)
      att[((size_t)(b * SEQN + row)) * DIMD + h * DH + d * 16 + lm] = f2bf(O[d][r] * inv);
  }
}

// ------- Proj GEMM + bias: A bf16, B fp32 (converted in staging), C fp32 ----
__global__ __launch_bounds__(256) void proj_gemm(
    const u16* __restrict__ A, const float* __restrict__ Bm,
    const float* __restrict__ bias, float* __restrict__ C) {
  __shared__ __align__(16) u16 la[128 * 40];
  __shared__ __align__(16) u16 lb[128 * 40];
  const int K = DIMD, N = DIMD;
  int tid = threadIdx.x;
  int bm = blockIdx.x, bn = blockIdx.y;
  int wid = tid >> 6, lane = tid & 63, lm = lane & 15, quad = lane >> 4;
  int wm = wid >> 1, wn = wid & 1;
  f32x4 acc[4][4] = {};
  const u16* Ab = A + (size_t)(bm * 128) * K;
  const float* Bb = Bm + (size_t)(bn * 128) * K;
  for (int k0 = 0; k0 < K; k0 += 32) {
    __syncthreads();
#pragma unroll
    for (int r = 0; r < 2; ++r) {
      int ch = tid + r * 256;
      int row = ch >> 2, cc = ch & 3;
      uint4 va = *(const uint4*)(Ab + (size_t)row * K + k0 + cc * 8);
      float4 f0 = *(const float4*)(Bb + (size_t)row * K + k0 + cc * 8);
      float4 f1 = *(const float4*)(Bb + (size_t)row * K + k0 + cc * 8 + 4);
      union { uint4 v; u16 s[8]; } wb;
      wb.s[0] = f2bf(f0.x); wb.s[1] = f2bf(f0.y);
      wb.s[2] = f2bf(f0.z); wb.s[3] = f2bf(f0.w);
      wb.s[4] = f2bf(f1.x); wb.s[5] = f2bf(f1.y);
      wb.s[6] = f2bf(f1.z); wb.s[7] = f2bf(f1.w);
      *(uint4*)&la[row * 40 + cc * 8] = va;
      *(uint4*)&lb[row * 40 + cc * 8] = wb.v;
    }
    __syncthreads();
    bf16x8 af[4], bfr[4];
#pragma unroll
    for (int i = 0; i < 4; ++i)
      af[i] = *(const bf16x8*)&la[(wm * 64 + i * 16 + lm) * 40 + quad * 8];
#pragma unroll
    for (int j = 0; j < 4; ++j)
      bfr[j] = *(const bf16x8*)&lb[(wn * 64 + j * 16 + lm) * 40 + quad * 8];
#pragma unroll
    for (int i = 0; i < 4; ++i)
#pragma unroll
      for (int j = 0; j < 4; ++j)
        acc[i][j] = __builtin_amdgcn_mfma_f32_16x16x32_bf16(af[i], bfr[j], acc[i][j], 0, 0, 0);
  }
#pragma unroll
  for (int i = 0; i < 4; ++i)
#pragma unroll
    for (int j = 0; j < 4; ++j) {
      int col = bn * 128 + wn * 64 + j * 16 + lm;
      float bv = bias[col];
#pragma unroll
      for (int r = 0; r < 4; ++r) {
        int rg = bm * 128 + wm * 64 + i * 16 + quad * 4 + r;
        C[(size_t)rg * N + col] = acc[i][j][r] + bv;
      }
    }
}

extern "C" void kernel_launch(void* const* d_in, const int* in_sizes, int n_in,
                              void* d_out, int out_size, void* d_ws, size_t ws_size,
                              hipStream_t stream) {
  const float* x      = (const float*)d_in[0];
  const float* w_qkv  = (const float*)d_in[1];
  const float* w_proj = (const float*)d_in[2];
  const float* b_proj = (const float*)d_in[3];
  const float* gamma  = (const float*)d_in[4];
  const float* beta   = (const float*)d_in[5];
  float* out = (float*)d_out;

  const size_t SZ = (size_t)MROWS * DIMD;  // 8388608 elements
  u16* xn  = (u16*)d_ws;
  u16* q   = xn + SZ;
  u16* kk  = q + SZ;
  u16* vt  = kk + SZ;
  u16* att = xn;  // reuse: xn dead after qkv_gemm

  ln_kernel<<<dim3(MROWS / 4), dim3(256), 0, stream>>>(x, gamma, beta, xn);
  qkv_gemm<<<dim3(MROWS / 128, (3 * DIMD) / 128), dim3(256), 0, stream>>>(
      xn, w_qkv, q, kk, vt);
  attn_kernel<<<dim3(SEQN / 64, BHN), dim3(256), 0, stream>>>(q, kk, vt, att);
  proj_gemm<<<dim3(MROWS / 128, DIMD / 128), dim3(256), 0, stream>>>(
      att, w_proj, b_proj, out);
}

// Round 3
// 417.878 us; speedup vs baseline: 1.5203x; 1.5203x over previous
//
#include <hip/hip_runtime.h>

typedef unsigned short u16;
typedef __bf16 bf16x8 __attribute__((ext_vector_type(8)));
typedef float f32x4 __attribute__((ext_vector_type(4)));

#define DIMD 512
#define SEQN 2048
#define NB   8
#define NH   8
#define DH   64
#define BHN  (NB*NH)          // 64
#define MROWS (NB*SEQN)       // 16384

__device__ __forceinline__ u16 f2bf(float f) {
  union { float f; unsigned u; } x; x.f = f;
  unsigned r = x.u + 0x7fffu + ((x.u >> 16) & 1u);
  return (u16)(r >> 16);
}

// ---------------- LayerNorm: one wave per row of 512. fp32 in -> bf16 out --
__global__ __launch_bounds__(256) void ln_kernel(
    const float* __restrict__ x, const float* __restrict__ gamma,
    const float* __restrict__ beta, u16* __restrict__ xn) {
  int row = blockIdx.x * 4 + (threadIdx.x >> 6);
  int lane = threadIdx.x & 63;
  const float* xr = x + (size_t)row * DIMD;
  float f[8], g[8], b[8];
  *(float4*)&f[0] = *(const float4*)(xr + lane * 8);
  *(float4*)&f[4] = *(const float4*)(xr + lane * 8 + 4);
  *(float4*)&g[0] = *(const float4*)(gamma + lane * 8);
  *(float4*)&g[4] = *(const float4*)(gamma + lane * 8 + 4);
  *(float4*)&b[0] = *(const float4*)(beta + lane * 8);
  *(float4*)&b[4] = *(const float4*)(beta + lane * 8 + 4);
  float sum = 0.f, sq = 0.f;
#pragma unroll
  for (int i = 0; i < 8; ++i) { sum += f[i]; sq += f[i] * f[i]; }
#pragma unroll
  for (int off = 1; off < 64; off <<= 1) {
    sum += __shfl_xor(sum, off, 64);
    sq  += __shfl_xor(sq, off, 64);
  }
  float mean = sum * (1.0f / DIMD);
  float var = sq * (1.0f / DIMD) - mean * mean;
  float rstd = rsqrtf(var + 1e-6f);
  union { uint4 v; u16 s[8]; } uo;
#pragma unroll
  for (int i = 0; i < 8; ++i)
    uo.s[i] = f2bf((f[i] - mean) * rstd * g[i] + b[i]);
  *(uint4*)(xn + (size_t)row * DIMD + lane * 8) = uo.v;
}

// ---------------- QKV GEMM: C[m,n] = xn[m,:] . w_qkv[n,:]  (B^T layout) ---
__global__ __launch_bounds__(256) void qkv_gemm(
    const u16* __restrict__ A, const float* __restrict__ Bm,
    u16* __restrict__ qo, u16* __restrict__ ko, u16* __restrict__ vto) {
  __shared__ __align__(16) u16 la[128 * 40];
  __shared__ __align__(16) u16 lb[128 * 40];
  const int K = DIMD;
  int tid = threadIdx.x;
  int bm = blockIdx.x, bn = blockIdx.y;
  int wid = tid >> 6, lane = tid & 63, lm = lane & 15, quad = lane >> 4;
  int wm = wid >> 1, wn = wid & 1;
  f32x4 acc[4][4] = {};
  const u16* Ab = A + (size_t)(bm * 128) * K;
  const float* Bb = Bm + (size_t)(bn * 128) * K;
  for (int k0 = 0; k0 < K; k0 += 32) {
    __syncthreads();
#pragma unroll
    for (int r = 0; r < 2; ++r) {
      int ch = tid + r * 256;
      int row = ch >> 2, cc = ch & 3;
      uint4 va = *(const uint4*)(Ab + (size_t)row * K + k0 + cc * 8);
      float4 f0 = *(const float4*)(Bb + (size_t)row * K + k0 + cc * 8);
      float4 f1 = *(const float4*)(Bb + (size_t)row * K + k0 + cc * 8 + 4);
      union { uint4 v; u16 s[8]; } wb;
      wb.s[0] = f2bf(f0.x); wb.s[1] = f2bf(f0.y);
      wb.s[2] = f2bf(f0.z); wb.s[3] = f2bf(f0.w);
      wb.s[4] = f2bf(f1.x); wb.s[5] = f2bf(f1.y);
      wb.s[6] = f2bf(f1.z); wb.s[7] = f2bf(f1.w);
      *(uint4*)&la[row * 40 + cc * 8] = va;
      *(uint4*)&lb[row * 40 + cc * 8] = wb.v;
    }
    __syncthreads();
    bf16x8 af[4], bfr[4];
#pragma unroll
    for (int i = 0; i < 4; ++i)
      af[i] = *(const bf16x8*)&la[(wm * 64 + i * 16 + lm) * 40 + quad * 8];
#pragma unroll
    for (int j = 0; j < 4; ++j)
      bfr[j] = *(const bf16x8*)&lb[(wn * 64 + j * 16 + lm) * 40 + quad * 8];
#pragma unroll
    for (int i = 0; i < 4; ++i)
#pragma unroll
      for (int j = 0; j < 4; ++j)
        acc[i][j] = __builtin_amdgcn_mfma_f32_16x16x32_bf16(af[i], bfr[j], acc[i][j], 0, 0, 0);
  }
#pragma unroll
  for (int i = 0; i < 4; ++i) {
#pragma unroll
    for (int j = 0; j < 4; ++j) {
      int col = bn * 128 + wn * 64 + j * 16 + lm;
      int part = col >> 9, rem = col & 511;
      int h = rem >> 6, d = rem & 63;
#pragma unroll
      for (int r = 0; r < 4; ++r) {
        int rg = bm * 128 + wm * 64 + i * 16 + quad * 4 + r;
        int b = rg >> 11, nn = rg & 2047;
        int bh = b * NH + h;
        u16 val = f2bf(acc[i][j][r]);
        if (part == 0)      qo[((size_t)bh * SEQN + nn) * DH + d] = val;
        else if (part == 1) ko[((size_t)bh * SEQN + nn) * DH + d] = val;
        else                vto[((size_t)bh * DH + d) * SEQN + nn] = val;
      }
    }
  }
}

// ---------------- Flash attention, S^T formulation ----------------
// grid: (SEQN/128, B*H), block 256 = 4 waves.
// Wave w owns 32 Q rows (2 groups of 16). S^T = mfma(K-frag, Q-frag):
// keys in quad*4+r, Q-rows across 16 lanes -> softmax reduce = in-reg + 2 shuffles.
// PV: O^T = mfma(V^T-frag, P^T-frag); P^T transits LDS as packed b64 writes.
__global__ __launch_bounds__(256, 4) void attn_kernel(
    const u16* __restrict__ q, const u16* __restrict__ k,
    const u16* __restrict__ vt, u16* __restrict__ att) {
  __shared__ __align__(16) u16 plds[4 * 2 * 2 * 16 * 72];  // 36864 B
  const float CEXP = 0.125f * 1.44269504f;  // scale * log2(e)
  int bh = blockIdx.y;
  int wid = threadIdx.x >> 6, lane = threadIdx.x & 63;
  int lm = lane & 15, quad = lane >> 4;
  int qbase = blockIdx.x * 128 + wid * 32;
  const u16* qb = q + (size_t)bh * SEQN * DH;
  const u16* kb = k + (size_t)bh * SEQN * DH;
  const u16* vb = vt + (size_t)bh * DH * SEQN;
  u16* pw = plds + wid * (2 * 2 * 16 * 72);

  bf16x8 qf[2][2];
#pragma unroll
  for (int g = 0; g < 2; ++g)
#pragma unroll
    for (int c = 0; c < 2; ++c)
      qf[g][c] = *(const bf16x8*)(qb + (size_t)(qbase + g * 16 + lm) * DH + c * 32 + quad * 8);

  f32x4 Ot[2][4] = {};
  float mrow[2], lrow[2];
  mrow[0] = mrow[1] = -1.0e30f;
  lrow[0] = lrow[1] = 0.f;

  int buf = 0;
  for (int j0 = 0; j0 < SEQN; j0 += 64, buf ^= 1) {
    // S^T: rows = keys (quad*4+r), cols = q-rows (lm)
    f32x4 s[2][4];
#pragma unroll
    for (int js = 0; js < 4; ++js) {
      bf16x8 kf0 = *(const bf16x8*)(kb + (size_t)(j0 + js * 16 + lm) * DH + quad * 8);
      bf16x8 kf1 = *(const bf16x8*)(kb + (size_t)(j0 + js * 16 + lm) * DH + 32 + quad * 8);
#pragma unroll
      for (int g = 0; g < 2; ++g) {
        f32x4 z = {0.f, 0.f, 0.f, 0.f};
        z = __builtin_amdgcn_mfma_f32_16x16x32_bf16(kf0, qf[g][0], z, 0, 0, 0);
        z = __builtin_amdgcn_mfma_f32_16x16x32_bf16(kf1, qf[g][1], z, 0, 0, 0);
        s[g][js] = z;
      }
    }
#pragma unroll
    for (int g = 0; g < 2; ++g) {
      float ml = s[g][0][0];
#pragma unroll
      for (int js = 0; js < 4; ++js)
#pragma unroll
        for (int r = 0; r < 4; ++r) ml = fmaxf(ml, s[g][js][r]);
      ml = fmaxf(ml, __shfl_xor(ml, 16, 64));
      ml = fmaxf(ml, __shfl_xor(ml, 32, 64));
      float mn = fmaxf(mrow[g], ml);
      float mnC = mn * CEXP;
      float alpha = exp2f(mrow[g] * CEXP - mnC);
      mrow[g] = mn;
      float rs = 0.f;
      u16* pg = pw + (g * 2 + buf) * (16 * 72);
#pragma unroll
      for (int js = 0; js < 4; ++js) {
        union { unsigned long long ll; u16 s4[4]; } pk;
#pragma unroll
        for (int r = 0; r < 4; ++r) {
          float p = exp2f(s[g][js][r] * CEXP - mnC);
          rs += p;
          pk.s4[r] = f2bf(p);
        }
        *(unsigned long long*)&pg[lm * 72 + js * 16 + quad * 4] = pk.ll;
      }
      rs += __shfl_xor(rs, 16, 64);
      rs += __shfl_xor(rs, 32, 64);
      lrow[g] = lrow[g] * alpha + rs;
#pragma unroll
      for (int db = 0; db < 4; ++db) Ot[g][db] *= alpha;
    }
    // P^T as B-fragment (lane = q-row, k = keys contiguous)
    bf16x8 pbf[2][2];
#pragma unroll
    for (int g = 0; g < 2; ++g) {
      const u16* pg = pw + (g * 2 + buf) * (16 * 72);
#pragma unroll
      for (int c = 0; c < 2; ++c)
        pbf[g][c] = *(const bf16x8*)&pg[lm * 72 + c * 32 + quad * 8];
    }
#pragma unroll
    for (int db = 0; db < 4; ++db) {
      bf16x8 va0 = *(const bf16x8*)(vb + (size_t)(db * 16 + lm) * SEQN + j0 + quad * 8);
      bf16x8 va1 = *(const bf16x8*)(vb + (size_t)(db * 16 + lm) * SEQN + j0 + 32 + quad * 8);
      Ot[0][db] = __builtin_amdgcn_mfma_f32_16x16x32_bf16(va0, pbf[0][0], Ot[0][db], 0, 0, 0);
      Ot[0][db] = __builtin_amdgcn_mfma_f32_16x16x32_bf16(va1, pbf[0][1], Ot[0][db], 0, 0, 0);
      Ot[1][db] = __builtin_amdgcn_mfma_f32_16x16x32_bf16(va0, pbf[1][0], Ot[1][db], 0, 0, 0);
      Ot[1][db] = __builtin_amdgcn_mfma_f32_16x16x32_bf16(va1, pbf[1][1], Ot[1][db], 0, 0, 0);
    }
  }
  // epilogue: O^T rows = d (quad*4+r within db*16 block), cols = q-row (lm)
  int b = bh >> 3, h = bh & 7;
#pragma unroll
  for (int g = 0; g < 2; ++g) {
    float inv = 1.0f / lrow[g];
    size_t rowoff = ((size_t)(b * SEQN + qbase + g * 16 + lm)) * DIMD + h * DH;
#pragma unroll
    for (int db = 0; db < 4; ++db) {
      union { unsigned long long ll; u16 s4[4]; } ok;
#pragma unroll
      for (int r = 0; r < 4; ++r) ok.s4[r] = f2bf(Ot[g][db][r] * inv);
      *(unsigned long long*)&att[rowoff + db * 16 + quad * 4] = ok.ll;
    }
  }
}

// ------- Proj GEMM + bias: A bf16, B fp32 (converted in staging), C fp32 ----
__global__ __launch_bounds__(256) void proj_gemm(
    const u16* __restrict__ A, const float* __restrict__ Bm,
    const float* __restrict__ bias, float* __restrict__ C) {
  __shared__ __align__(16) u16 la[128 * 40];
  __shared__ __align__(16) u16 lb[128 * 40];
  const int K = DIMD, N = DIMD;
  int tid = threadIdx.x;
  int bm = blockIdx.x, bn = blockIdx.y;
  int wid = tid >> 6, lane = tid & 63, lm = lane & 15, quad = lane >> 4;
  int wm = wid >> 1, wn = wid & 1;
  f32x4 acc[4][4] = {};
  const u16* Ab = A + (size_t)(bm * 128) * K;
  const float* Bb = Bm + (size_t)(bn * 128) * K;
  for (int k0 = 0; k0 < K; k0 += 32) {
    __syncthreads();
#pragma unroll
    for (int r = 0; r < 2; ++r) {
      int ch = tid + r * 256;
      int row = ch >> 2, cc = ch & 3;
      uint4 va = *(const uint4*)(Ab + (size_t)row * K + k0 + cc * 8);
      float4 f0 = *(const float4*)(Bb + (size_t)row * K + k0 + cc * 8);
      float4 f1 = *(const float4*)(Bb + (size_t)row * K + k0 + cc * 8 + 4);
      union { uint4 v; u16 s[8]; } wb;
      wb.s[0] = f2bf(f0.x); wb.s[1] = f2bf(f0.y);
      wb.s[2] = f2bf(f0.z); wb.s[3] = f2bf(f0.w);
      wb.s[4] = f2bf(f1.x); wb.s[5] = f2bf(f1.y);
      wb.s[6] = f2bf(f1.z); wb.s[7] = f2bf(f1.w);
      *(uint4*)&la[row * 40 + cc * 8] = va;
      *(uint4*)&lb[row * 40 + cc * 8] = wb.v;
    }
    __syncthreads();
    bf16x8 af[4], bfr[4];
#pragma unroll
    for (int i = 0; i < 4; ++i)
      af[i] = *(const bf16x8*)&la[(wm * 64 + i * 16 + lm) * 40 + quad * 8];
#pragma unroll
    for (int j = 0; j < 4; ++j)
      bfr[j] = *(const bf16x8*)&lb[(wn * 64 + j * 16 + lm) * 40 + quad * 8];
#pragma unroll
    for (int i = 0; i < 4; ++i)
#pragma unroll
      for (int j = 0; j < 4; ++j)
        acc[i][j] = __builtin_amdgcn_mfma_f32_16x16x32_bf16(af[i], bfr[j], acc[i][j], 0, 0, 0);
  }
#pragma unroll
  for (int i = 0; i < 4; ++i)
#pragma unroll
    for (int j = 0; j < 4; ++j) {
      int col = bn * 128 + wn * 64 + j * 16 + lm;
      float bv = bias[col];
#pragma unroll
      for (int r = 0; r < 4; ++r) {
        int rg = bm * 128 + wm * 64 + i * 16 + quad * 4 + r;
        C[(size_t)rg * N + col] = acc[i][j][r] + bv;
      }
    }
}

extern "C" void kernel_launch(void* const* d_in, const int* in_sizes, int n_in,
                              void* d_out, int out_size, void* d_ws, size_t ws_size,
                              hipStream_t stream) {
  const float* x      = (const float*)d_in[0];
  const float* w_qkv  = (const float*)d_in[1];
  const float* w_proj = (const float*)d_in[2];
  const float* b_proj = (const float*)d_in[3];
  const float* gamma  = (const float*)d_in[4];
  const float* beta   = (const float*)d_in[5];
  float* out = (float*)d_out;

  const size_t SZ = (size_t)MROWS * DIMD;  // 8388608 elements
  u16* xn  = (u16*)d_ws;
  u16* q   = xn + SZ;
  u16* kk  = q + SZ;
  u16* vt  = kk + SZ;
  u16* att = xn;  // reuse: xn dead after qkv_gemm

  ln_kernel<<<dim3(MROWS / 4), dim3(256), 0, stream>>>(x, gamma, beta, xn);
  qkv_gemm<<<dim3(MROWS / 128, (3 * DIMD) / 128), dim3(256), 0, stream>>>(
      xn, w_qkv, q, kk, vt);
  attn_kernel<<<dim3(SEQN / 128, BHN), dim3(256), 0, stream>>>(q, kk, vt, att);
  proj_gemm<<<dim3(MROWS / 128, DIMD / 128), dim3(256), 0, stream>>>(
      att, w_proj, b_proj, out);
}